// Round 10
// baseline (202.725 us; speedup 1.0000x reference)
//
#include <hip/hip_runtime.h>

// SimpleSNN: T=16, B=4096, N_IN=784, N_HID=256, N_OUT=10
//   conv_x      : X fp32 {0,1} -> Xq i8, K padded 784->832
//   conv_w3     : W1 -> 3 i8 planes, w = 2^-11 a + 2^-18 b + 2^-25 c
//                 (residual <= 2^-26; i32 MFMA accumulation exact)
//   gemm1_lif1  : FUSED gemm1+lif1, t-tiled x4: per group of 4 timesteps keep
//                 acc[4][2][3] live -> 24 MFMA per k-step (ILP hides A-load
//                 latency), B frags read once per k-step per group (t-invariant).
//                 LIF state in regs; writes z1 i8 only. Zero barriers in loop.
//   gemm2_f32   : z1 i8 -> fp32 (exact), identical dot order
//   lif2        : unchanged

#define T_STEPS 16
#define B_SZ    4096
#define N_IN    784
#define N_HID   256
#define N_OUT   10
#define M_TOT   (T_STEPS * B_SZ)   // 65536
#define KP8     832                // 13 * 64
#define WPLANE  (N_HID * KP8)      // i8 elems per W plane
#define WROW    848                // padded LDS row stride: 2-way banks only
#define WPL     (16 * WROW)        // per-plane LDS bytes (13568)

typedef int    i32x4 __attribute__((ext_vector_type(4)));
typedef unsigned int u32;
typedef unsigned char u8;

// ---------------- conv_x: fp32 {0,1} -> i8, pad K 784->832 -----------------
__global__ __launch_bounds__(256) void conv_x(
    const float* __restrict__ X, u8* __restrict__ Xq)
{
    const long idx = (long)blockIdx.x * 256 + threadIdx.x;   // < 65536*52
    const long m = idx / 52;
    const int  s = (int)(idx - m * 52);
    uint4 o = make_uint4(0u, 0u, 0u, 0u);
    if (s < 49) {                                  // 49*16 = 784 exactly
        const uint4* src = reinterpret_cast<const uint4*>(X + m * N_IN + s * 16);
        const uint4 f0 = src[0], f1 = src[1], f2 = src[2], f3 = src[3];
        auto pk = [](uint4 f) -> u32 {
            return (f.x ? 1u : 0u) | ((f.y ? 1u : 0u) << 8) |
                   ((f.z ? 1u : 0u) << 16) | ((f.w ? 1u : 0u) << 24);
        };
        o.x = pk(f0); o.y = pk(f1); o.z = pk(f2); o.w = pk(f3);
    }
    reinterpret_cast<uint4*>(Xq)[idx] = o;
}

// ---------------- conv_w3: W1 -> 3 i8 planes (power-of-2 scales) -----------
__global__ __launch_bounds__(256) void conv_w3(
    const float* __restrict__ W1, char* __restrict__ Wq)
{
    const int idx = blockIdx.x * 256 + threadIdx.x;   // over 256*832
    if (idx >= N_HID * KP8) return;
    const int n = idx / KP8, k = idx % KP8;
    const float w = (k < N_IN) ? W1[n * N_IN + k] : 0.0f;
    const float a = rintf(w * 2048.0f);                       // s1 = 2^-11
    const float r1 = fmaf(a, -4.8828125e-4f, w);
    const float b = rintf(r1 * 262144.0f);                    // s2 = 2^-18
    const float r2 = fmaf(b, -3.814697265625e-6f, r1);
    const float c = rintf(r2 * 33554432.0f);                  // s3 = 2^-25
    Wq[idx]              = (char)(int)a;
    Wq[WPLANE + idx]     = (char)(int)b;
    Wq[2 * WPLANE + idx] = (char)(int)c;
}

// ---------------- gemm1 + lif1 fused, t-tiled x4 ---------------------------
__global__ __launch_bounds__(256, 2) void gemm1_lif1(
    const u8* __restrict__ Xq,
    const u8* __restrict__ Wq,
    const float* __restrict__ b1,
    u8* __restrict__ Z1)
{
    __shared__ u8 Bq[3 * WPL];          // 40,704 B

    const int tid  = threadIdx.x;
    const int lane = tid & 63;
    const int w    = tid >> 6;          // wave 0..3: rows w*32..+32
    // XCD grouping: all 16 n-slices of one b-tile on one XCD
    const int bid = blockIdx.x;
    const int l   = (bid & 7) * 64 + (bid >> 3);
    const int b0  = (l >> 4) * 128;
    const int n0  = (l & 15) * 16;
    const int ls  = lane >> 4;          // k-slice 0..3 (16 B each)
    const int lr  = lane & 15;

    // ---- W -> LDS via regs (padded row stride 848 -> 2-way aliasing only) ----
    #pragma unroll
    for (int it = 0; it < 10; ++it) {
        const int u = it * 256 + tid;                 // 3*16*52 = 2496 units
        if (u < 2496) {
            const int plane = u / 832;
            const int rem   = u - plane * 832;
            const int row   = rem / 52;               // col within slice
            const int sp    = rem - row * 52;         // 16B slot
            const uint4 v = *reinterpret_cast<const uint4*>(
                Wq + (size_t)plane * WPLANE + (size_t)(n0 + row) * KP8 + sp * 16);
            *reinterpret_cast<uint4*>(&Bq[plane * WPL + row * WROW + sp * 16]) = v;
        }
    }
    __syncthreads();                    // the only barrier

    const float bb = b1[n0 + lr];
    float vS[8], cS[8];                 // LIF state per (i,q) = i*4+q
    #pragma unroll
    for (int k = 0; k < 8; ++k) { vS[k] = 0.0f; cS[k] = 0.0f; }

    int bO[3];
    #pragma unroll
    for (int p = 0; p < 3; ++p) bO[p] = p * WPL + lr * WROW + (ls << 4);

    const size_t TSTR = (size_t)B_SZ * KP8;
    const u8* aP0 = Xq + (size_t)(b0 + w * 32 + lr) * KP8 + ls * 16;  // frag i=0
    const u8* aP1 = aP0 + 16 * KP8;                                    // frag i=1

    const float s1 = 4.8828125e-4f;          // 2^-11
    const float s2 = 3.814697265625e-6f;     // 2^-18
    const float s3 = 2.9802322387695312e-8f; // 2^-25

    for (int g = 0; g < 4; ++g) {       // 4 groups x 4 timesteps
        i32x4 acc[4][2][3];
        #pragma unroll
        for (int tt = 0; tt < 4; ++tt)
            #pragma unroll
            for (int i = 0; i < 2; ++i)
                #pragma unroll
                for (int p = 0; p < 3; ++p)
                    acc[tt][i][p] = (i32x4){0, 0, 0, 0};

        uint4 ab[2][4][2];              // [parity][tt][frag]
        #pragma unroll
        for (int tt = 0; tt < 4; ++tt) {
            const u8* p0 = aP0 + (size_t)tt * TSTR;
            const u8* p1 = aP1 + (size_t)tt * TSTR;
            ab[0][tt][0] = *reinterpret_cast<const uint4*>(p0);
            ab[0][tt][1] = *reinterpret_cast<const uint4*>(p1);
            ab[1][tt][0] = *reinterpret_cast<const uint4*>(p0 + 64);
            ab[1][tt][1] = *reinterpret_cast<const uint4*>(p1 + 64);
        }

        #pragma unroll
        for (int j = 0; j < 13; ++j) {
            const int pb = j & 1;
            uint4 bf[3];
            #pragma unroll
            for (int p = 0; p < 3; ++p)
                bf[p] = *reinterpret_cast<const uint4*>(&Bq[bO[p] + j * 64]);

            #pragma unroll
            for (int tt = 0; tt < 4; ++tt)
                #pragma unroll
                for (int i = 0; i < 2; ++i)
                    #pragma unroll
                    for (int p = 0; p < 3; ++p)
                        acc[tt][i][p] = __builtin_amdgcn_mfma_i32_16x16x64_i8(
                            __builtin_bit_cast(i32x4, ab[pb][tt][i]),
                            __builtin_bit_cast(i32x4, bf[p]),
                            acc[tt][i][p], 0, 0, 0);

            if (j < 11) {               // prefetch j+2 (same parity; WAR after use)
                #pragma unroll
                for (int tt = 0; tt < 4; ++tt) {
                    const u8* p0 = aP0 + (size_t)tt * TSTR + (j + 2) * 64;
                    const u8* p1 = aP1 + (size_t)tt * TSTR + (j + 2) * 64;
                    ab[pb][tt][0] = *reinterpret_cast<const uint4*>(p0);
                    ab[pb][tt][1] = *reinterpret_cast<const uint4*>(p1);
                }
            }
        }
        aP0 += 4 * TSTR; aP1 += 4 * TSTR;

        // LIF for the 4 timesteps, in order; write spikes as i8
        #pragma unroll
        for (int tt = 0; tt < 4; ++tt) {
            const int t = 4 * g + tt;
            #pragma unroll
            for (int i = 0; i < 2; ++i) {
                #pragma unroll
                for (int q = 0; q < 4; ++q) {
                    const int k = i * 4 + q;
                    const float c1 = fmaf(s1, (float)acc[tt][i][0][q],
                                     fmaf(s2, (float)acc[tt][i][1][q],
                                     fmaf(s3, (float)acc[tt][i][2][q], bb)));
                    const float vd = vS[k] + 0.1f * ((0.0f - vS[k]) + cS[k]);
                    const float id = cS[k] - 0.2f * cS[k];
                    const bool  sp = vd > 1.0f;
                    Z1[(size_t)(t * B_SZ + b0 + w * 32 + i * 16 + ls * 4 + q) * N_HID
                       + n0 + lr] = sp ? (u8)1 : (u8)0;
                    vS[k] = sp ? 0.0f : vd;
                    cS[k] = id + c1;
                }
            }
        }
    }
}

// ---------------- GEMM2: z1 i8 -> fp32 (exact), K=256, N=10 ----------------
__global__ __launch_bounds__(640) void gemm2_f32(
    const u8* __restrict__ Z, const float* __restrict__ W2,
    const float* __restrict__ b2, float* __restrict__ C2)
{
    __shared__ float zs[64 * 268];
    __shared__ float ws[N_OUT * N_HID];
    const int tid = threadIdx.x;
    const int m0 = blockIdx.x * 64;

    for (int c = tid; c < 1024; c += 640) {          // 64 rows x 16 chunks
        const int r = c >> 4;
        const int col = (c & 15) * 16;
        const uint4 v = *reinterpret_cast<const uint4*>(
            Z + (size_t)(m0 + r) * N_HID + col);
        float* d = &zs[r * 268 + col];
        const u32 wd[4] = {v.x, v.y, v.z, v.w};
        #pragma unroll
        for (int k = 0; k < 4; ++k)
            #pragma unroll
            for (int b = 0; b < 4; ++b)
                d[k * 4 + b] = (float)((wd[k] >> (8 * b)) & 0xffu);
    }
    *(float4*)&ws[tid * 4] = *(const float4*)&W2[tid * 4];
    __syncthreads();

    const int o = tid >> 6;
    const int r = tid & 63;
    float acc = b2[o];
    #pragma unroll
    for (int k = 0; k < N_HID; k += 4) {
        const float4 z4 = *(const float4*)&zs[r * 268 + k];
        const float4 w4 = *(const float4*)&ws[o * N_HID + k];
        acc += z4.x * w4.x + z4.y * w4.y + z4.z * w4.z + z4.w * w4.w;
    }
    C2[(size_t)(m0 + r) * N_OUT + o] = acc;
}

// ---------------- LIF2: per (b,o), loop t; accumulate spike count ----------
__global__ __launch_bounds__(256) void lif2_kernel(
    const float* __restrict__ C2, float* __restrict__ out)
{
    const int g = blockIdx.x * 256 + threadIdx.x;
    const int stride = B_SZ * N_OUT;
    float v = 0.0f, cur = 0.0f, s = 0.0f;
    #pragma unroll
    for (int t = 0; t < T_STEPS; ++t) {
        const float c = C2[t * stride + g];
        const float vd = v + 0.1f * ((0.0f - v) + cur);
        const float id = cur - 0.2f * cur;
        const bool  sp = vd > 1.0f;
        s += sp ? 1.0f : 0.0f;
        v = sp ? 0.0f : vd;
        cur = id + c;
    }
    out[g] = s;
}

extern "C" void kernel_launch(void* const* d_in, const int* in_sizes, int n_in,
                              void* d_out, int out_size, void* d_ws, size_t ws_size,
                              hipStream_t stream)
{
    const float* X  = (const float*)d_in[0];
    const float* W1 = (const float*)d_in[1];
    const float* b1 = (const float*)d_in[2];
    const float* W2 = (const float*)d_in[3];
    const float* b2 = (const float*)d_in[4];
    float* out = (float*)d_out;

    // ws: [Wq 0.64MB | pad->1MB][Xq 54.5MB][Z1 16.8MB][C2 2.6MB]
    char* Wq = (char*)d_ws;
    u8*   Xq = (u8*)d_ws + (1 << 20);
    u8*   Z1 = Xq + (size_t)M_TOT * KP8;
    float* C2 = (float*)(Z1 + (size_t)M_TOT * N_HID);

    conv_x<<<(M_TOT * (KP8 / 16)) / 256, 256, 0, stream>>>(X, Xq);

    conv_w3<<<(N_HID * KP8) / 256, 256, 0, stream>>>(W1, Wq);

    gemm1_lif1<<<512, 256, 0, stream>>>(Xq, (const u8*)Wq, b1, Z1);

    gemm2_f32<<<M_TOT / 64, 640, 0, stream>>>(Z1, W2, b2, C2);

    lif2_kernel<<<(B_SZ * N_OUT) / 256, 256, 0, stream>>>(C2, out);
}

// Round 11
// 138.683 us; speedup vs baseline: 1.4618x; 1.4618x over previous
//
#include <hip/hip_runtime.h>

// SimpleSNN: T=16, B=4096, N_IN=784, N_HID=256, N_OUT=10
//   conv_x      : X fp32 {0,1} -> Xq i8, K padded 784->832
//   conv_w3     : W1 -> 3 i8 planes, w = 2^-11 a + 2^-18 b + 2^-25 c
//                 (residual <= 2^-26; i32 MFMA accumulation exact)
//   gemm1_lif1  : FUSED gemm1+lif1, t-tiled x2 with FULL double-prefetch:
//                 A (global) and B (LDS) both ping-pong one k-step ahead in
//                 named register buffers; 12 MFMA/step hide the latency.
//                 B frags shared across the 2 timesteps. LIF state in regs;
//                 writes z1 i8 only. Zero barriers in the loop.
//   gemm2_f32   : z1 i8 -> fp32 (exact), identical dot order
//   lif2        : unchanged

#define T_STEPS 16
#define B_SZ    4096
#define N_IN    784
#define N_HID   256
#define N_OUT   10
#define M_TOT   (T_STEPS * B_SZ)   // 65536
#define KP8     832                // 13 * 64
#define WPLANE  (N_HID * KP8)      // i8 elems per W plane
#define WROW    848                // padded LDS row stride: 2-way banks only
#define WPL     (16 * WROW)        // per-plane LDS bytes (13568)

typedef int    i32x4 __attribute__((ext_vector_type(4)));
typedef unsigned int u32;
typedef unsigned char u8;

// ---------------- conv_x: fp32 {0,1} -> i8, pad K 784->832 -----------------
__global__ __launch_bounds__(256) void conv_x(
    const float* __restrict__ X, u8* __restrict__ Xq)
{
    const long idx = (long)blockIdx.x * 256 + threadIdx.x;   // < 65536*52
    const long m = idx / 52;
    const int  s = (int)(idx - m * 52);
    uint4 o = make_uint4(0u, 0u, 0u, 0u);
    if (s < 49) {                                  // 49*16 = 784 exactly
        const uint4* src = reinterpret_cast<const uint4*>(X + m * N_IN + s * 16);
        const uint4 f0 = src[0], f1 = src[1], f2 = src[2], f3 = src[3];
        auto pk = [](uint4 f) -> u32 {
            return (f.x ? 1u : 0u) | ((f.y ? 1u : 0u) << 8) |
                   ((f.z ? 1u : 0u) << 16) | ((f.w ? 1u : 0u) << 24);
        };
        o.x = pk(f0); o.y = pk(f1); o.z = pk(f2); o.w = pk(f3);
    }
    reinterpret_cast<uint4*>(Xq)[idx] = o;
}

// ---------------- conv_w3: W1 -> 3 i8 planes (power-of-2 scales) -----------
__global__ __launch_bounds__(256) void conv_w3(
    const float* __restrict__ W1, char* __restrict__ Wq)
{
    const int idx = blockIdx.x * 256 + threadIdx.x;   // over 256*832
    if (idx >= N_HID * KP8) return;
    const int n = idx / KP8, k = idx % KP8;
    const float w = (k < N_IN) ? W1[n * N_IN + k] : 0.0f;
    const float a = rintf(w * 2048.0f);                       // s1 = 2^-11
    const float r1 = fmaf(a, -4.8828125e-4f, w);
    const float b = rintf(r1 * 262144.0f);                    // s2 = 2^-18
    const float r2 = fmaf(b, -3.814697265625e-6f, r1);
    const float c = rintf(r2 * 33554432.0f);                  // s3 = 2^-25
    Wq[idx]              = (char)(int)a;
    Wq[WPLANE + idx]     = (char)(int)b;
    Wq[2 * WPLANE + idx] = (char)(int)c;
}

// ---------------- gemm1 + lif1 fused, t-tiled x2, dual prefetch ------------
__global__ __launch_bounds__(256, 2) void gemm1_lif1(
    const u8* __restrict__ Xq,
    const u8* __restrict__ Wq,
    const float* __restrict__ b1,
    u8* __restrict__ Z1)
{
    __shared__ u8 Bq[3 * WPL];          // 40,704 B

    const int tid  = threadIdx.x;
    const int lane = tid & 63;
    const int w    = tid >> 6;          // wave 0..3: rows w*32..+32
    // XCD grouping: all 16 n-slices of one b-tile on one XCD
    const int bid = blockIdx.x;
    const int l   = (bid & 7) * 64 + (bid >> 3);
    const int b0  = (l >> 4) * 128;
    const int n0  = (l & 15) * 16;
    const int ls  = lane >> 4;          // k-slice 0..3 (16 B each)
    const int lr  = lane & 15;

    // ---- W -> LDS via regs (padded row stride 848 -> 2-way aliasing only) ----
    #pragma unroll
    for (int it = 0; it < 10; ++it) {
        const int u = it * 256 + tid;                 // 3*16*52 = 2496 units
        if (u < 2496) {
            const int plane = u / 832;
            const int rem   = u - plane * 832;
            const int row   = rem / 52;               // col within slice
            const int sp    = rem - row * 52;         // 16B slot
            const uint4 v = *reinterpret_cast<const uint4*>(
                Wq + (size_t)plane * WPLANE + (size_t)(n0 + row) * KP8 + sp * 16);
            *reinterpret_cast<uint4*>(&Bq[plane * WPL + row * WROW + sp * 16]) = v;
        }
    }
    __syncthreads();                    // the only barrier

    const float bb = b1[n0 + lr];
    float vS[8], cS[8];                 // LIF state per (i,q) = i*4+q
    #pragma unroll
    for (int k = 0; k < 8; ++k) { vS[k] = 0.0f; cS[k] = 0.0f; }

    int bO[3];
    #pragma unroll
    for (int p = 0; p < 3; ++p) bO[p] = p * WPL + lr * WROW + (ls << 4);

    const size_t TSTR = (size_t)B_SZ * KP8;
    // A base pointers per (tt, frag): advanced by 2*TSTR per group
    const u8* aB[2][2];
    aB[0][0] = Xq + (size_t)(b0 + w * 32 + lr) * KP8 + ls * 16;
    aB[0][1] = aB[0][0] + 16 * KP8;
    aB[1][0] = aB[0][0] + TSTR;
    aB[1][1] = aB[0][1] + TSTR;

    const float s1 = 4.8828125e-4f;          // 2^-11
    const float s2 = 3.814697265625e-6f;     // 2^-18
    const float s3 = 2.9802322387695312e-8f; // 2^-25

    for (int g = 0; g < 8; ++g) {       // 8 groups x 2 timesteps
        i32x4 acc[2][2][3];
        #pragma unroll
        for (int tt = 0; tt < 2; ++tt)
            #pragma unroll
            for (int i = 0; i < 2; ++i)
                #pragma unroll
                for (int p = 0; p < 3; ++p)
                    acc[tt][i][p] = (i32x4){0, 0, 0, 0};

        uint4 a0[2][2], a1[2][2];       // named ping-pong (static indexing)
        uint4 f0[3], f1[3];

        auto loadA = [&](uint4 (&dst)[2][2], int s) {
            #pragma unroll
            for (int tt = 0; tt < 2; ++tt)
                #pragma unroll
                for (int i = 0; i < 2; ++i)
                    dst[tt][i] = *reinterpret_cast<const uint4*>(aB[tt][i] + s * 64);
        };
        auto loadB = [&](uint4 (&dst)[3], int s) {
            #pragma unroll
            for (int p = 0; p < 3; ++p)
                dst[p] = *reinterpret_cast<const uint4*>(&Bq[bO[p] + s * 64]);
        };
        auto mm = [&](uint4 (&A)[2][2], uint4 (&B)[3]) {
            __builtin_amdgcn_s_setprio(1);
            #pragma unroll
            for (int tt = 0; tt < 2; ++tt)
                #pragma unroll
                for (int i = 0; i < 2; ++i)
                    #pragma unroll
                    for (int p = 0; p < 3; ++p)
                        acc[tt][i][p] = __builtin_amdgcn_mfma_i32_16x16x64_i8(
                            __builtin_bit_cast(i32x4, A[tt][i]),
                            __builtin_bit_cast(i32x4, B[p]),
                            acc[tt][i][p], 0, 0, 0);
            __builtin_amdgcn_s_setprio(0);
        };

        loadA(a0, 0); loadB(f0, 0);
        #pragma unroll
        for (int s = 0; s < 12; s += 2) {
            loadA(a1, s + 1); loadB(f1, s + 1);   // prefetch s+1
            mm(a0, f0);                            // compute s
            loadA(a0, s + 2); loadB(f0, s + 2);   // prefetch s+2 (<=12)
            mm(a1, f1);                            // compute s+1
        }
        mm(a0, f0);                                // step 12

        // advance A bases to next group
        aB[0][0] += 2 * TSTR; aB[0][1] += 2 * TSTR;
        aB[1][0] += 2 * TSTR; aB[1][1] += 2 * TSTR;

        // LIF for the 2 timesteps, in order; write spikes as i8
        #pragma unroll
        for (int tt = 0; tt < 2; ++tt) {
            const int t = 2 * g + tt;
            #pragma unroll
            for (int i = 0; i < 2; ++i) {
                #pragma unroll
                for (int q = 0; q < 4; ++q) {
                    const int k = i * 4 + q;
                    const float c1 = fmaf(s1, (float)acc[tt][i][0][q],
                                     fmaf(s2, (float)acc[tt][i][1][q],
                                     fmaf(s3, (float)acc[tt][i][2][q], bb)));
                    const float vd = vS[k] + 0.1f * ((0.0f - vS[k]) + cS[k]);
                    const float id = cS[k] - 0.2f * cS[k];
                    const bool  sp = vd > 1.0f;
                    Z1[(size_t)(t * B_SZ + b0 + w * 32 + i * 16 + ls * 4 + q) * N_HID
                       + n0 + lr] = sp ? (u8)1 : (u8)0;
                    vS[k] = sp ? 0.0f : vd;
                    cS[k] = id + c1;
                }
            }
        }
    }
}

// ---------------- GEMM2: z1 i8 -> fp32 (exact), K=256, N=10 ----------------
__global__ __launch_bounds__(640) void gemm2_f32(
    const u8* __restrict__ Z, const float* __restrict__ W2,
    const float* __restrict__ b2, float* __restrict__ C2)
{
    __shared__ float zs[64 * 268];
    __shared__ float ws[N_OUT * N_HID];
    const int tid = threadIdx.x;
    const int m0 = blockIdx.x * 64;

    for (int c = tid; c < 1024; c += 640) {          // 64 rows x 16 chunks
        const int r = c >> 4;
        const int col = (c & 15) * 16;
        const uint4 v = *reinterpret_cast<const uint4*>(
            Z + (size_t)(m0 + r) * N_HID + col);
        float* d = &zs[r * 268 + col];
        const u32 wd[4] = {v.x, v.y, v.z, v.w};
        #pragma unroll
        for (int k = 0; k < 4; ++k)
            #pragma unroll
            for (int b = 0; b < 4; ++b)
                d[k * 4 + b] = (float)((wd[k] >> (8 * b)) & 0xffu);
    }
    *(float4*)&ws[tid * 4] = *(const float4*)&W2[tid * 4];
    __syncthreads();

    const int o = tid >> 6;
    const int r = tid & 63;
    float acc = b2[o];
    #pragma unroll
    for (int k = 0; k < N_HID; k += 4) {
        const float4 z4 = *(const float4*)&zs[r * 268 + k];
        const float4 w4 = *(const float4*)&ws[o * N_HID + k];
        acc += z4.x * w4.x + z4.y * w4.y + z4.z * w4.z + z4.w * w4.w;
    }
    C2[(size_t)(m0 + r) * N_OUT + o] = acc;
}

// ---------------- LIF2: per (b,o), loop t; accumulate spike count ----------
__global__ __launch_bounds__(256) void lif2_kernel(
    const float* __restrict__ C2, float* __restrict__ out)
{
    const int g = blockIdx.x * 256 + threadIdx.x;
    const int stride = B_SZ * N_OUT;
    float v = 0.0f, cur = 0.0f, s = 0.0f;
    #pragma unroll
    for (int t = 0; t < T_STEPS; ++t) {
        const float c = C2[t * stride + g];
        const float vd = v + 0.1f * ((0.0f - v) + cur);
        const float id = cur - 0.2f * cur;
        const bool  sp = vd > 1.0f;
        s += sp ? 1.0f : 0.0f;
        v = sp ? 0.0f : vd;
        cur = id + c;
    }
    out[g] = s;
}

extern "C" void kernel_launch(void* const* d_in, const int* in_sizes, int n_in,
                              void* d_out, int out_size, void* d_ws, size_t ws_size,
                              hipStream_t stream)
{
    const float* X  = (const float*)d_in[0];
    const float* W1 = (const float*)d_in[1];
    const float* b1 = (const float*)d_in[2];
    const float* W2 = (const float*)d_in[3];
    const float* b2 = (const float*)d_in[4];
    float* out = (float*)d_out;

    // ws: [Wq 0.64MB | pad->1MB][Xq 54.5MB][Z1 16.8MB][C2 2.6MB]
    char* Wq = (char*)d_ws;
    u8*   Xq = (u8*)d_ws + (1 << 20);
    u8*   Z1 = Xq + (size_t)M_TOT * KP8;
    float* C2 = (float*)(Z1 + (size_t)M_TOT * N_HID);

    conv_x<<<(M_TOT * (KP8 / 16)) / 256, 256, 0, stream>>>(X, Xq);

    conv_w3<<<(N_HID * KP8) / 256, 256, 0, stream>>>(W1, Wq);

    gemm1_lif1<<<512, 256, 0, stream>>>(Xq, (const u8*)Wq, b1, Z1);

    gemm2_f32<<<M_TOT / 64, 640, 0, stream>>>(Z1, W2, b2, C2);

    lif2_kernel<<<(B_SZ * N_OUT) / 256, 256, 0, stream>>>(C2, out);
}